// Round 7
// baseline (974.966 us; speedup 1.0000x reference)
//
#include <hip/hip_runtime.h>
#include <stdint.h>

#define B_ 4
#define T_ 4096
#define D_ 1024
#define H_ 32
#define NX_ 12
#define NV_ 32
#define NCOL 1408          // 384 wx cols + 1024 wv cols
#define TAU 2e-4f          // |acc| below this -> recompute dot in f64 (~13 sigma)
#define BITW 88            // u16 words per bitmat row (1408/16)

typedef __attribute__((ext_vector_type(8))) short short8v;
typedef __attribute__((ext_vector_type(4))) float floatx4;

static __device__ __forceinline__ unsigned short bf16_rne(float f) {
  unsigned u = __float_as_uint(f);
  return (unsigned short)((u + 0x7FFFu + ((u >> 16) & 1u)) >> 16);
}
static __device__ __forceinline__ float bf16_to_f32(unsigned short h) {
  return __uint_as_float(((unsigned)h) << 16);
}

// MFMA 16x16x32 bf16 fragment k-permutation (verified absmax=0, rounds 4/6):
// operand elems 0-3 = k {4g..4g+3}, elems 4-7 = k {16+4g..16+4g+3}, g=lane>>4.
//
// WT layout (fragment/lane-major, one wave-load = contiguous 1KB):
//   WT[((ks*88 + ct)*2 + hl)*512 + lane*8 + e]
// ks = k/32, ct = col/16, hl = 0(hi)/1(lo), lane = g*16 + (col&15), e = 0..7.

// ---------------------------------------------------------------------------
// Kernel 0: split W (f32) -> WT bf16 hi/lo in fragment-major layout.
// ---------------------------------------------------------------------------
__global__ __launch_bounds__(256) void wsplit_kernel(
    const float* __restrict__ wx, const float* __restrict__ wv,
    unsigned short* __restrict__ WT)
{
  __shared__ float tile[64][65];
  const int tid = threadIdx.x;
  const int cb = blockIdx.x % (NCOL / 64);   // col tile (22)
  const int kb = blockIdx.x / (NCOL / 64);   // k tile (16)
  const int c_local = tid & 63;
  const int c_glob = cb * 64 + c_local;

#pragma unroll
  for (int i = 0; i < 16; ++i) {
    const int k_local = (tid >> 6) + i * 4;
    const int k_glob = kb * 64 + k_local;
    const float v = (c_glob < 384) ? wx[k_glob * 384 + c_glob]
                                   : wv[k_glob * 1024 + (c_glob - 384)];
    tile[k_local][c_local] = v;
  }
  __syncthreads();

#pragma unroll
  for (int i = 0; i < 4; ++i) {
    const int q = (tid >> 6) * 4 + i;        // quad index 0..15
    const int k0 = q * 4;                    // local k base
    const int ks32 = kb * 2 + (k0 >> 5);     // global 32-k block
    const int r = k0 & 31;
    const int g = (r < 16) ? (r >> 2) : ((r - 16) >> 2);
    const int half = (r < 16) ? 0 : 1;
    const int lane = g * 16 + (c_glob & 15);
    const int ct = c_glob >> 4;
    const long base = ((long)ks32 * 88 + ct) * 1024 + lane * 8 + half * 4;
    ushort4 hv, lv;
    float f0 = tile[k0 + 0][c_local], f1 = tile[k0 + 1][c_local];
    float f2 = tile[k0 + 2][c_local], f3 = tile[k0 + 3][c_local];
    hv.x = bf16_rne(f0); lv.x = bf16_rne(f0 - bf16_to_f32(hv.x));
    hv.y = bf16_rne(f1); lv.y = bf16_rne(f1 - bf16_to_f32(hv.y));
    hv.z = bf16_rne(f2); lv.z = bf16_rne(f2 - bf16_to_f32(hv.z));
    hv.w = bf16_rne(f3); lv.w = bf16_rne(f3 - bf16_to_f32(hv.w));
    *(ushort4*)&WT[base] = hv;               // hi block (hl=0)
    *(ushort4*)&WT[base + 512] = lv;         // lo block (hl=1)
  }
}

// ---------------------------------------------------------------------------
// Kernel 1: S = x @ [wx|wv] via split-bf16 MFMA. LDS-FREE, BARRIER-FREE:
// B frags load as contiguous 1KB wave-loads from WT; A loads f32 from x
// (full-line gathers) and splits hi/lo in-register. 2-deep software pipeline
// with named register sets. Epilogue (verified) unchanged.
// ---------------------------------------------------------------------------
__global__ __launch_bounds__(256, 2) void gemm_kernel(
    const float* __restrict__ x,
    const unsigned short* __restrict__ WT,
    const float* __restrict__ wx, const float* __restrict__ wv,
    unsigned short* __restrict__ bitmat)
{
  const int tid = threadIdx.x;
  const int wid = tid >> 6, lane = tid & 63;
  const int wr = wid >> 1, wc = wid & 1;
  // bijective chunked XCD swizzle (1408 = 8 * 176)
  const int sw = (blockIdx.x & 7) * 176 + (blockIdx.x >> 3);
  const int bx = sw % 11;                    // N tile (fast -> A-panel sharing)
  const int by = sw / 11;                    // M tile

  const int ln15 = lane & 15, g = lane >> 4;
  const int g4 = g * 4;
  const int ct0 = bx * 8 + wc * 4;
  const float* xA = x + (size_t)(by * 128 + wr * 64 + ln15) * 1024;

  floatx4 acc[4][4];
#pragma unroll
  for (int i = 0; i < 4; ++i)
#pragma unroll
    for (int j = 0; j < 4; ++j) acc[i][j] = (floatx4)0.f;

  float4 Aa0[4], Ab0[4], Aa1[4], Ab1[4];
  short8v Bh0[4], Bl0[4], Bh1[4], Bl1[4];

#define LOAD_A(DA, DB, KS)                                                    \
  {                                                                           \
    _Pragma("unroll")                                                         \
    for (int mi = 0; mi < 4; ++mi) {                                          \
      const float* xp = xA + (size_t)mi * 16384 + (KS) * 32 + g4;             \
      DA[mi] = *(const float4*)xp;                                            \
      DB[mi] = *(const float4*)(xp + 16);                                     \
    }                                                                         \
  }

#define LOAD_B(DH, DL, KS)                                                    \
  {                                                                           \
    _Pragma("unroll")                                                         \
    for (int nj = 0; nj < 4; ++nj) {                                          \
      const unsigned short* wp =                                              \
          WT + ((size_t)(KS) * 88 + ct0 + nj) * 1024 + lane * 8;              \
      DH[nj] = *(const short8v*)wp;                                           \
      DL[nj] = *(const short8v*)(wp + 512);                                   \
    }                                                                         \
  }

#define SPLIT1(dst_h, dst_l, f, e)                                            \
  {                                                                           \
    const unsigned short hh = bf16_rne(f);                                    \
    dst_h[e] = (short)hh;                                                     \
    dst_l[e] = (short)bf16_rne((f)-bf16_to_f32(hh));                          \
  }

#define COMPUTE(SA, SB, BH, BL)                                               \
  {                                                                           \
    short8v ah[4], al[4];                                                     \
    _Pragma("unroll")                                                         \
    for (int mi = 0; mi < 4; ++mi) {                                          \
      SPLIT1(ah[mi], al[mi], SA[mi].x, 0)                                     \
      SPLIT1(ah[mi], al[mi], SA[mi].y, 1)                                     \
      SPLIT1(ah[mi], al[mi], SA[mi].z, 2)                                     \
      SPLIT1(ah[mi], al[mi], SA[mi].w, 3)                                     \
      SPLIT1(ah[mi], al[mi], SB[mi].x, 4)                                     \
      SPLIT1(ah[mi], al[mi], SB[mi].y, 5)                                     \
      SPLIT1(ah[mi], al[mi], SB[mi].z, 6)                                     \
      SPLIT1(ah[mi], al[mi], SB[mi].w, 7)                                     \
    }                                                                         \
    _Pragma("unroll")                                                         \
    for (int mi = 0; mi < 4; ++mi)                                            \
      _Pragma("unroll")                                                       \
      for (int nj = 0; nj < 4; ++nj) {                                        \
        acc[mi][nj] = __builtin_amdgcn_mfma_f32_16x16x32_bf16(                \
            ah[mi], BH[nj], acc[mi][nj], 0, 0, 0);                            \
        acc[mi][nj] = __builtin_amdgcn_mfma_f32_16x16x32_bf16(                \
            ah[mi], BL[nj], acc[mi][nj], 0, 0, 0);                            \
        acc[mi][nj] = __builtin_amdgcn_mfma_f32_16x16x32_bf16(                \
            al[mi], BH[nj], acc[mi][nj], 0, 0, 0);                            \
      }                                                                       \
  }

  LOAD_A(Aa0, Ab0, 0)
  LOAD_B(Bh0, Bl0, 0)
#pragma unroll 1
  for (int t = 0; t < 16; ++t) {
    const int ks = 2 * t;
    if (t < 15) { LOAD_A(Aa1, Ab1, ks + 1) LOAD_B(Bh1, Bl1, ks + 1) }
    else        { LOAD_A(Aa1, Ab1, 31)     LOAD_B(Bh1, Bl1, 31) }
    COMPUTE(Aa0, Ab0, Bh0, Bl0)
    if (t < 15) { LOAD_A(Aa0, Ab0, ks + 2) LOAD_B(Bh0, Bl0, ks + 2) }
    COMPUTE(Aa1, Ab1, Bh1, Bl1)
  }

  // ---- epilogue: sign bits (f64 fallback near zero) -> ballot -> bitmat ----
#pragma unroll
  for (int mi = 0; mi < 4; ++mi)
#pragma unroll
    for (int nj = 0; nj < 4; ++nj) {
      const int colg = bx * 128 + wc * 64 + nj * 16 + (lane & 15);
      const int rowbase = by * 128 + wr * 64 + mi * 16 + ((lane >> 4) * 4);
      const int col16 = bx * 8 + wc * 4 + nj;
#pragma unroll
      for (int r = 0; r < 4; ++r) {
        const float v = acc[mi][nj][r];
        bool pos = v > 0.f;
        if (fabsf(v) < TAU) {               // rare: exact f64 recompute
          const float* xr = x + (long)(rowbase + r) * 1024;
          const float* wp; int ldw;
          if (colg < 384) { wp = wx + colg; ldw = 384; }
          else            { wp = wv + (colg - 384); ldw = 1024; }
          double s0 = 0, s1 = 0, s2 = 0, s3 = 0;
          for (int d = 0; d < 1024; d += 4) {
            s0 = fma((double)xr[d + 0], (double)wp[(long)(d + 0) * ldw], s0);
            s1 = fma((double)xr[d + 1], (double)wp[(long)(d + 1) * ldw], s1);
            s2 = fma((double)xr[d + 2], (double)wp[(long)(d + 2) * ldw], s2);
            s3 = fma((double)xr[d + 3], (double)wp[(long)(d + 3) * ldw], s3);
          }
          pos = ((s0 + s1) + (s2 + s3)) > 0.0;
        }
        const unsigned long long mask = __ballot(pos);
        if ((lane & 15) == 0)
          bitmat[(long)(rowbase + r) * BITW + col16] =
              (unsigned short)((mask >> (lane & 48)) & 0xFFFFull);
      }
    }
}

// ---------------------------------------------------------------------------
// Kernel 2: bitmat rows -> packed keys (12b) and values (32b), [B,H,T].
// ---------------------------------------------------------------------------
__global__ __launch_bounds__(256) void pack_kernel(
    const unsigned short* __restrict__ bitmat,
    unsigned short* __restrict__ kxg, unsigned int* __restrict__ kvg)
{
  const int gid = blockIdx.x * 256 + threadIdx.x;
  const int row = gid >> 5;                  // b*T + t
  const int h = gid & 31;
  const int b = row >> 12, t = row & (T_ - 1);
  const unsigned short* bp = bitmat + (long)row * BITW;
  const int bitpos = h * NX_;
  const int w0 = bitpos >> 4, off = bitpos & 15;
  const unsigned int v32 = (unsigned int)bp[w0] | ((unsigned int)bp[w0 + 1] << 16);
  const unsigned int key = (v32 >> off) & 0xFFFu;
  const unsigned int val = (unsigned int)bp[24 + 2 * h] |
                           ((unsigned int)bp[25 + 2 * h] << 16);
  const long sidx = ((long)b * H_ + h) * T_ + t;
  kxg[sidx] = (unsigned short)key;
  kvg[sidx] = val;
}

// ---------------------------------------------------------------------------
// Kernel 3: sequential associative-memory scan per (b,h) stream (unchanged).
// ---------------------------------------------------------------------------
#define CH 1024
#define UNR 16

__global__ __launch_bounds__(256) void scan_kernel(
    const unsigned short* __restrict__ kxg,
    const unsigned int* __restrict__ kvg,
    unsigned int* __restrict__ yg)
{
  __shared__ unsigned int table[1 << NX_];
  __shared__ unsigned int kbuf[CH], vbuf[CH], ybuf[CH];
  const int tid = threadIdx.x;
  const long base = (long)blockIdx.x * T_;

#pragma unroll
  for (int i = 0; i < (1 << NX_) / 256; ++i) table[tid + 256 * i] = 0u;

  for (int c = 0; c < T_ / CH; ++c) {
    __syncthreads();
#pragma unroll
    for (int i = 0; i < CH / 256; ++i) {
      kbuf[tid + 256 * i] = kxg[base + c * CH + tid + 256 * i];
      vbuf[tid + 256 * i] = kvg[base + c * CH + tid + 256 * i];
    }
    __syncthreads();
    if (tid == 0) {
      for (int i = 0; i < CH; i += UNR) {
        unsigned int k[UNR], v[UNR], y[UNR];
#pragma unroll
        for (int u = 0; u < UNR; ++u) { k[u] = kbuf[i + u]; v[u] = vbuf[i + u]; }
#pragma unroll
        for (int u = 0; u < UNR; ++u) { y[u] = table[k[u]]; table[k[u]] = v[u]; }
#pragma unroll
        for (int u = 0; u < UNR; ++u) ybuf[i + u] = y[u];
      }
    }
    __syncthreads();
#pragma unroll
    for (int i = 0; i < CH / 256; ++i)
      yg[base + c * CH + tid + 256 * i] = ybuf[tid + 256 * i];
  }
}

// ---------------------------------------------------------------------------
// Kernel 4: expand recalled value bits into f32 embeddings (unchanged).
// ---------------------------------------------------------------------------
__global__ __launch_bounds__(256) void out_kernel(
    const unsigned int* __restrict__ yg,
    const float* __restrict__ e0, const float* __restrict__ e1,
    float* __restrict__ out)
{
  const int tid = threadIdx.x;
  const int bt = blockIdx.x;
  const int b = bt >> 12, t = bt & (T_ - 1);
  const int h = tid >> 3;
  const unsigned int y = yg[((long)b * H_ + h) * T_ + t];
  const int d0 = tid * 4;
  const int vsh = (tid & 7) * 4;
  float4 o;
  o.x = ((y >> (vsh + 0)) & 1) ? e1[d0 + 0] : e0[d0 + 0];
  o.y = ((y >> (vsh + 1)) & 1) ? e1[d0 + 1] : e0[d0 + 1];
  o.z = ((y >> (vsh + 2)) & 1) ? e1[d0 + 2] : e0[d0 + 2];
  o.w = ((y >> (vsh + 3)) & 1) ? e1[d0 + 3] : e0[d0 + 3];
  *(float4*)&out[(long)bt * D_ + d0] = o;
}

// ---------------------------------------------------------------------------
extern "C" void kernel_launch(void* const* d_in, const int* in_sizes, int n_in,
                              void* d_out, int out_size, void* d_ws, size_t ws_size,
                              hipStream_t stream)
{
  const float* x  = (const float*)d_in[0];
  const float* wx = (const float*)d_in[1];
  const float* wv = (const float*)d_in[2];
  const float* e0 = (const float*)d_in[3];
  const float* e1 = (const float*)d_in[4];

  char* ws = (char*)d_ws;
  const size_t MB = 1u << 20;
  unsigned short* WT     = (unsigned short*)(ws + 0 * MB);   // 5.77 MB
  unsigned short* bitmat = (unsigned short*)(ws + 6 * MB);   // 2.875 MB
  unsigned short* kxg    = (unsigned short*)(ws + 9 * MB);   // 1 MB
  unsigned int*   kvg    = (unsigned int*)  (ws + 10 * MB);  // 2 MB
  unsigned int*   yg     = (unsigned int*)  (ws + 12 * MB);  // 2 MB (14 MB total)
  float* out = (float*)d_out;

  hipLaunchKernelGGL(wsplit_kernel, dim3((NCOL / 64) * 16), dim3(256), 0, stream,
                     wx, wv, WT);
  hipLaunchKernelGGL(gemm_kernel, dim3(11 * 128), dim3(256), 0, stream,
                     x, WT, wx, wv, bitmat);
  hipLaunchKernelGGL(pack_kernel, dim3(2048), dim3(256), 0, stream,
                     bitmat, kxg, kvg);
  hipLaunchKernelGGL(scan_kernel, dim3(B_ * H_), dim3(256), 0, stream,
                     kxg, kvg, yg);
  hipLaunchKernelGGL(out_kernel, dim3(B_ * T_), dim3(256), 0, stream,
                     yg, e0, e1, out);
}

// Round 8
// 740.811 us; speedup vs baseline: 1.3161x; 1.3161x over previous
//
#include <hip/hip_runtime.h>
#include <stdint.h>

#define B_ 4
#define T_ 4096
#define D_ 1024
#define H_ 32
#define NX_ 12
#define NV_ 32
#define NCOL 1408          // 384 wx cols + 1024 wv cols
#define TAU 2e-4f          // |acc| below this -> recompute dot in f64 (~13 sigma)
#define BITW 88            // u16 words per bitmat row (1408/16)

typedef __attribute__((ext_vector_type(8))) short short8v;
typedef __attribute__((ext_vector_type(4))) float floatx4;

static __device__ __forceinline__ unsigned short bf16_rne(float f) {
  unsigned u = __float_as_uint(f);
  return (unsigned short)((u + 0x7FFFu + ((u >> 16) & 1u)) >> 16);
}
static __device__ __forceinline__ float bf16_to_f32(unsigned short h) {
  return __uint_as_float(((unsigned)h) << 16);
}

// MFMA 16x16x32 bf16 fragment k-permutation (verified absmax=0, rounds 4/6/7):
// operand elems 0-3 = k {4g..4g+3}, elems 4-7 = k {16+4g..16+4g+3}, g=lane>>4.
//
// WT layout (verified round 7): WT[((ks*88 + ct)*2 + hl)*512 + lane*8 + e],
//   lane = g*16 + (col&15).
// XT layout (new, same pattern over rows): XTh/XTl[(ks*1024 + rt)*512 +
//   lane*8 + e], lane = g*16 + (row&15), rt = row>>4.

// ---------------------------------------------------------------------------
// Kernel 0a: split W (f32) -> WT bf16 hi/lo in fragment-major layout.
// ---------------------------------------------------------------------------
__global__ __launch_bounds__(256) void wsplit_kernel(
    const float* __restrict__ wx, const float* __restrict__ wv,
    unsigned short* __restrict__ WT)
{
  __shared__ float tile[64][65];
  const int tid = threadIdx.x;
  const int cb = blockIdx.x % (NCOL / 64);   // col tile (22)
  const int kb = blockIdx.x / (NCOL / 64);   // k tile (16)
  const int c_local = tid & 63;
  const int c_glob = cb * 64 + c_local;

#pragma unroll
  for (int i = 0; i < 16; ++i) {
    const int k_local = (tid >> 6) + i * 4;
    const int k_glob = kb * 64 + k_local;
    const float v = (c_glob < 384) ? wx[k_glob * 384 + c_glob]
                                   : wv[k_glob * 1024 + (c_glob - 384)];
    tile[k_local][c_local] = v;
  }
  __syncthreads();

#pragma unroll
  for (int i = 0; i < 4; ++i) {
    const int q = (tid >> 6) * 4 + i;        // quad index 0..15
    const int k0 = q * 4;                    // local k base
    const int ks32 = kb * 2 + (k0 >> 5);     // global 32-k block
    const int kr = k0 & 31;
    const int half = kr >> 4;
    const int g = (kr & 15) >> 2;
    const int lane = g * 16 + (c_glob & 15);
    const int ct = c_glob >> 4;
    const long base = ((long)ks32 * 88 + ct) * 1024 + lane * 8 + half * 4;
    ushort4 hv, lv;
    float f0 = tile[k0 + 0][c_local], f1 = tile[k0 + 1][c_local];
    float f2 = tile[k0 + 2][c_local], f3 = tile[k0 + 3][c_local];
    hv.x = bf16_rne(f0); lv.x = bf16_rne(f0 - bf16_to_f32(hv.x));
    hv.y = bf16_rne(f1); lv.y = bf16_rne(f1 - bf16_to_f32(hv.y));
    hv.z = bf16_rne(f2); lv.z = bf16_rne(f2 - bf16_to_f32(hv.z));
    hv.w = bf16_rne(f3); lv.w = bf16_rne(f3 - bf16_to_f32(hv.w));
    *(ushort4*)&WT[base] = hv;               // hi block (hl=0)
    *(ushort4*)&WT[base + 512] = lv;         // lo block (hl=1)
  }
}

// ---------------------------------------------------------------------------
// Kernel 0b: split x (f32) -> XTh/XTl bf16 in A-fragment-major layout.
// One float4 per thread; coalesced reads.
// ---------------------------------------------------------------------------
__global__ __launch_bounds__(256) void xsplit_kernel(
    const float* __restrict__ x,
    unsigned short* __restrict__ XTh, unsigned short* __restrict__ XTl)
{
  const long q = (long)blockIdx.x * 256 + threadIdx.x;  // quad id
  const int row = (int)(q >> 8);
  const int k0 = ((int)q & 255) * 4;
  const float4 f = *(const float4*)(x + (long)row * 1024 + k0);
  const int rt = row >> 4, r15 = row & 15;
  const int ks = k0 >> 5, kr = k0 & 31;
  const int half = kr >> 4;
  const int g = (kr & 15) >> 2;
  const int lane = g * 16 + r15;
  const long base = ((long)ks * 1024 + rt) * 512 + lane * 8 + half * 4;
  ushort4 hv, lv;
  hv.x = bf16_rne(f.x); lv.x = bf16_rne(f.x - bf16_to_f32(hv.x));
  hv.y = bf16_rne(f.y); lv.y = bf16_rne(f.y - bf16_to_f32(hv.y));
  hv.z = bf16_rne(f.z); lv.z = bf16_rne(f.z - bf16_to_f32(hv.z));
  hv.w = bf16_rne(f.w); lv.w = bf16_rne(f.w - bf16_to_f32(hv.w));
  *(ushort4*)&XTh[base] = hv;
  *(ushort4*)&XTl[base] = lv;
}

// ---------------------------------------------------------------------------
// Kernel 1 (fast): S = x @ [wx|wv] via split-bf16 MFMA. LDS-free,
// barrier-free, split-free: A and B fragments are contiguous 1KB wave-loads.
// Single register set (~80 VGPR + 64 acc) -> no spills, 8 waves/CU.
// ---------------------------------------------------------------------------
__global__ __launch_bounds__(256, 2) void gemm_kernel(
    const float* __restrict__ x,
    const unsigned short* __restrict__ XTh,
    const unsigned short* __restrict__ XTl,
    const unsigned short* __restrict__ WT,
    const float* __restrict__ wx, const float* __restrict__ wv,
    unsigned short* __restrict__ bitmat)
{
  const int tid = threadIdx.x;
  const int wid = tid >> 6, lane = tid & 63;
  const int wr = wid >> 1, wc = wid & 1;
  // bijective chunked XCD swizzle (1408 = 8 * 176)
  const int sw = (blockIdx.x & 7) * 176 + (blockIdx.x >> 3);
  const int bx = sw % 11;                    // N tile (fast -> A-panel sharing)
  const int by = sw / 11;                    // M tile

  const int rt0 = by * 8 + wr * 4;           // A row-tile base (16-row tiles)
  const int ct0 = bx * 8 + wc * 4;           // B col-tile base (16-col tiles)
  const int l8 = lane * 8;

  floatx4 acc[4][4];
#pragma unroll
  for (int i = 0; i < 4; ++i)
#pragma unroll
    for (int j = 0; j < 4; ++j) acc[i][j] = (floatx4)0.f;

#pragma unroll 2
  for (int ks = 0; ks < 32; ++ks) {
    short8v ah[4], al[4], bh[4], bl[4];
#pragma unroll
    for (int mi = 0; mi < 4; ++mi) {
      const long abase = ((long)ks * 1024 + rt0 + mi) * 512 + l8;
      ah[mi] = *(const short8v*)&XTh[abase];
      al[mi] = *(const short8v*)&XTl[abase];
    }
#pragma unroll
    for (int nj = 0; nj < 4; ++nj) {
      const long wbase = ((long)ks * 88 + ct0 + nj) * 1024 + l8;
      bh[nj] = *(const short8v*)&WT[wbase];
      bl[nj] = *(const short8v*)&WT[wbase + 512];
    }
#pragma unroll
    for (int mi = 0; mi < 4; ++mi)
#pragma unroll
      for (int nj = 0; nj < 4; ++nj) {
        acc[mi][nj] = __builtin_amdgcn_mfma_f32_16x16x32_bf16(
            ah[mi], bh[nj], acc[mi][nj], 0, 0, 0);
        acc[mi][nj] = __builtin_amdgcn_mfma_f32_16x16x32_bf16(
            ah[mi], bl[nj], acc[mi][nj], 0, 0, 0);
        acc[mi][nj] = __builtin_amdgcn_mfma_f32_16x16x32_bf16(
            al[mi], bh[nj], acc[mi][nj], 0, 0, 0);
      }
  }

  // ---- epilogue: sign bits (f64 fallback near zero) -> ballot -> bitmat ----
#pragma unroll
  for (int mi = 0; mi < 4; ++mi)
#pragma unroll
    for (int nj = 0; nj < 4; ++nj) {
      const int colg = bx * 128 + wc * 64 + nj * 16 + (lane & 15);
      const int rowbase = by * 128 + wr * 64 + mi * 16 + ((lane >> 4) * 4);
      const int col16 = bx * 8 + wc * 4 + nj;
#pragma unroll
      for (int r = 0; r < 4; ++r) {
        const float v = acc[mi][nj][r];
        bool pos = v > 0.f;
        if (fabsf(v) < TAU) {               // rare: exact f64 recompute
          const float* xr = x + (long)(rowbase + r) * 1024;
          const float* wp; int ldw;
          if (colg < 384) { wp = wx + colg; ldw = 384; }
          else            { wp = wv + (colg - 384); ldw = 1024; }
          double s0 = 0, s1 = 0, s2 = 0, s3 = 0;
          for (int d = 0; d < 1024; d += 4) {
            s0 = fma((double)xr[d + 0], (double)wp[(long)(d + 0) * ldw], s0);
            s1 = fma((double)xr[d + 1], (double)wp[(long)(d + 1) * ldw], s1);
            s2 = fma((double)xr[d + 2], (double)wp[(long)(d + 2) * ldw], s2);
            s3 = fma((double)xr[d + 3], (double)wp[(long)(d + 3) * ldw], s3);
          }
          pos = ((s0 + s1) + (s2 + s3)) > 0.0;
        }
        const unsigned long long mask = __ballot(pos);
        if ((lane & 15) == 0)
          bitmat[(long)(rowbase + r) * BITW + col16] =
              (unsigned short)((mask >> (lane & 48)) & 0xFFFFull);
      }
    }
}

// ---------------------------------------------------------------------------
// Kernel 1 (fallback, round-7 version — used only if ws_size < 78 MB).
// ---------------------------------------------------------------------------
__global__ __launch_bounds__(256, 2) void gemm_fb_kernel(
    const float* __restrict__ x,
    const unsigned short* __restrict__ WT,
    const float* __restrict__ wx, const float* __restrict__ wv,
    unsigned short* __restrict__ bitmat)
{
  const int tid = threadIdx.x;
  const int wid = tid >> 6, lane = tid & 63;
  const int wr = wid >> 1, wc = wid & 1;
  const int sw = (blockIdx.x & 7) * 176 + (blockIdx.x >> 3);
  const int bx = sw % 11;
  const int by = sw / 11;

  const int ln15 = lane & 15, g = lane >> 4;
  const int g4 = g * 4;
  const int ct0 = bx * 8 + wc * 4;
  const float* xA = x + (size_t)(by * 128 + wr * 64 + ln15) * 1024;

  floatx4 acc[4][4];
#pragma unroll
  for (int i = 0; i < 4; ++i)
#pragma unroll
    for (int j = 0; j < 4; ++j) acc[i][j] = (floatx4)0.f;

#pragma unroll 1
  for (int ks = 0; ks < 32; ++ks) {
    float4 Aa[4], Ab[4];
    short8v bh[4], bl[4];
#pragma unroll
    for (int mi = 0; mi < 4; ++mi) {
      const float* xp = xA + (size_t)mi * 16384 + ks * 32 + g4;
      Aa[mi] = *(const float4*)xp;
      Ab[mi] = *(const float4*)(xp + 16);
    }
#pragma unroll
    for (int nj = 0; nj < 4; ++nj) {
      const unsigned short* wp =
          WT + ((size_t)ks * 88 + ct0 + nj) * 1024 + lane * 8;
      bh[nj] = *(const short8v*)wp;
      bl[nj] = *(const short8v*)(wp + 512);
    }
    short8v ah[4], al[4];
#pragma unroll
    for (int mi = 0; mi < 4; ++mi) {
      const float fe[8] = {Aa[mi].x, Aa[mi].y, Aa[mi].z, Aa[mi].w,
                           Ab[mi].x, Ab[mi].y, Ab[mi].z, Ab[mi].w};
#pragma unroll
      for (int e = 0; e < 8; ++e) {
        const unsigned short hh = bf16_rne(fe[e]);
        ah[mi][e] = (short)hh;
        al[mi][e] = (short)bf16_rne(fe[e] - bf16_to_f32(hh));
      }
    }
#pragma unroll
    for (int mi = 0; mi < 4; ++mi)
#pragma unroll
      for (int nj = 0; nj < 4; ++nj) {
        acc[mi][nj] = __builtin_amdgcn_mfma_f32_16x16x32_bf16(
            ah[mi], bh[nj], acc[mi][nj], 0, 0, 0);
        acc[mi][nj] = __builtin_amdgcn_mfma_f32_16x16x32_bf16(
            ah[mi], bl[nj], acc[mi][nj], 0, 0, 0);
        acc[mi][nj] = __builtin_amdgcn_mfma_f32_16x16x32_bf16(
            al[mi], bh[nj], acc[mi][nj], 0, 0, 0);
      }
  }

#pragma unroll
  for (int mi = 0; mi < 4; ++mi)
#pragma unroll
    for (int nj = 0; nj < 4; ++nj) {
      const int colg = bx * 128 + wc * 64 + nj * 16 + (lane & 15);
      const int rowbase = by * 128 + wr * 64 + mi * 16 + ((lane >> 4) * 4);
      const int col16 = bx * 8 + wc * 4 + nj;
#pragma unroll
      for (int r = 0; r < 4; ++r) {
        const float v = acc[mi][nj][r];
        bool pos = v > 0.f;
        if (fabsf(v) < TAU) {
          const float* xr = x + (long)(rowbase + r) * 1024;
          const float* wp; int ldw;
          if (colg < 384) { wp = wx + colg; ldw = 384; }
          else            { wp = wv + (colg - 384); ldw = 1024; }
          double s0 = 0, s1 = 0, s2 = 0, s3 = 0;
          for (int d = 0; d < 1024; d += 4) {
            s0 = fma((double)xr[d + 0], (double)wp[(long)(d + 0) * ldw], s0);
            s1 = fma((double)xr[d + 1], (double)wp[(long)(d + 1) * ldw], s1);
            s2 = fma((double)xr[d + 2], (double)wp[(long)(d + 2) * ldw], s2);
            s3 = fma((double)xr[d + 3], (double)wp[(long)(d + 3) * ldw], s3);
          }
          pos = ((s0 + s1) + (s2 + s3)) > 0.0;
        }
        const unsigned long long mask = __ballot(pos);
        if ((lane & 15) == 0)
          bitmat[(long)(rowbase + r) * BITW + col16] =
              (unsigned short)((mask >> (lane & 48)) & 0xFFFFull);
      }
    }
}

// ---------------------------------------------------------------------------
// Kernel 2: bitmat rows -> packed keys (12b) and values (32b), [B,H,T].
// ---------------------------------------------------------------------------
__global__ __launch_bounds__(256) void pack_kernel(
    const unsigned short* __restrict__ bitmat,
    unsigned short* __restrict__ kxg, unsigned int* __restrict__ kvg)
{
  const int gid = blockIdx.x * 256 + threadIdx.x;
  const int row = gid >> 5;                  // b*T + t
  const int h = gid & 31;
  const int b = row >> 12, t = row & (T_ - 1);
  const unsigned short* bp = bitmat + (long)row * BITW;
  const int bitpos = h * NX_;
  const int w0 = bitpos >> 4, off = bitpos & 15;
  const unsigned int v32 = (unsigned int)bp[w0] | ((unsigned int)bp[w0 + 1] << 16);
  const unsigned int key = (v32 >> off) & 0xFFFu;
  const unsigned int val = (unsigned int)bp[24 + 2 * h] |
                           ((unsigned int)bp[25 + 2 * h] << 16);
  const long sidx = ((long)b * H_ + h) * T_ + t;
  kxg[sidx] = (unsigned short)key;
  kvg[sidx] = val;
}

// ---------------------------------------------------------------------------
// Kernel 3: sequential associative-memory scan per (b,h) stream (unchanged).
// ---------------------------------------------------------------------------
#define CH 1024
#define UNR 16

__global__ __launch_bounds__(256) void scan_kernel(
    const unsigned short* __restrict__ kxg,
    const unsigned int* __restrict__ kvg,
    unsigned int* __restrict__ yg)
{
  __shared__ unsigned int table[1 << NX_];
  __shared__ unsigned int kbuf[CH], vbuf[CH], ybuf[CH];
  const int tid = threadIdx.x;
  const long base = (long)blockIdx.x * T_;

#pragma unroll
  for (int i = 0; i < (1 << NX_) / 256; ++i) table[tid + 256 * i] = 0u;

  for (int c = 0; c < T_ / CH; ++c) {
    __syncthreads();
#pragma unroll
    for (int i = 0; i < CH / 256; ++i) {
      kbuf[tid + 256 * i] = kxg[base + c * CH + tid + 256 * i];
      vbuf[tid + 256 * i] = kvg[base + c * CH + tid + 256 * i];
    }
    __syncthreads();
    if (tid == 0) {
      for (int i = 0; i < CH; i += UNR) {
        unsigned int k[UNR], v[UNR], y[UNR];
#pragma unroll
        for (int u = 0; u < UNR; ++u) { k[u] = kbuf[i + u]; v[u] = vbuf[i + u]; }
#pragma unroll
        for (int u = 0; u < UNR; ++u) { y[u] = table[k[u]]; table[k[u]] = v[u]; }
#pragma unroll
        for (int u = 0; u < UNR; ++u) ybuf[i + u] = y[u];
      }
    }
    __syncthreads();
#pragma unroll
    for (int i = 0; i < CH / 256; ++i)
      yg[base + c * CH + tid + 256 * i] = ybuf[tid + 256 * i];
  }
}

// ---------------------------------------------------------------------------
// Kernel 4: expand recalled value bits into f32 embeddings (unchanged).
// ---------------------------------------------------------------------------
__global__ __launch_bounds__(256) void out_kernel(
    const unsigned int* __restrict__ yg,
    const float* __restrict__ e0, const float* __restrict__ e1,
    float* __restrict__ out)
{
  const int tid = threadIdx.x;
  const int bt = blockIdx.x;
  const int b = bt >> 12, t = bt & (T_ - 1);
  const int h = tid >> 3;
  const unsigned int y = yg[((long)b * H_ + h) * T_ + t];
  const int d0 = tid * 4;
  const int vsh = (tid & 7) * 4;
  float4 o;
  o.x = ((y >> (vsh + 0)) & 1) ? e1[d0 + 0] : e0[d0 + 0];
  o.y = ((y >> (vsh + 1)) & 1) ? e1[d0 + 1] : e0[d0 + 1];
  o.z = ((y >> (vsh + 2)) & 1) ? e1[d0 + 2] : e0[d0 + 2];
  o.w = ((y >> (vsh + 3)) & 1) ? e1[d0 + 3] : e0[d0 + 3];
  *(float4*)&out[(long)bt * D_ + d0] = o;
}

// ---------------------------------------------------------------------------
extern "C" void kernel_launch(void* const* d_in, const int* in_sizes, int n_in,
                              void* d_out, int out_size, void* d_ws, size_t ws_size,
                              hipStream_t stream)
{
  const float* x  = (const float*)d_in[0];
  const float* wx = (const float*)d_in[1];
  const float* wv = (const float*)d_in[2];
  const float* e0 = (const float*)d_in[3];
  const float* e1 = (const float*)d_in[4];

  char* ws = (char*)d_ws;
  const size_t MB = 1u << 20;
  unsigned short* WT     = (unsigned short*)(ws + 0 * MB);   // 5.77 MB
  unsigned short* bitmat = (unsigned short*)(ws + 6 * MB);   // 2.875 MB
  unsigned short* kxg    = (unsigned short*)(ws + 9 * MB);   // 1 MB
  unsigned int*   kvg    = (unsigned int*)  (ws + 10 * MB);  // 2 MB
  unsigned int*   yg     = (unsigned int*)  (ws + 12 * MB);  // 2 MB
  unsigned short* XTh    = (unsigned short*)(ws + 14 * MB);  // 32 MB
  unsigned short* XTl    = (unsigned short*)(ws + 46 * MB);  // 32 MB (78 total)
  float* out = (float*)d_out;

  const bool fast = ws_size >= (size_t)78 * MB;

  hipLaunchKernelGGL(wsplit_kernel, dim3((NCOL / 64) * 16), dim3(256), 0, stream,
                     wx, wv, WT);
  if (fast) {
    hipLaunchKernelGGL(xsplit_kernel, dim3(16384), dim3(256), 0, stream,
                       x, XTh, XTl);
    hipLaunchKernelGGL(gemm_kernel, dim3(11 * 128), dim3(256), 0, stream,
                       x, XTh, XTl, WT, wx, wv, bitmat);
  } else {
    hipLaunchKernelGGL(gemm_fb_kernel, dim3(11 * 128), dim3(256), 0, stream,
                       x, WT, wx, wv, bitmat);
  }
  hipLaunchKernelGGL(pack_kernel, dim3(2048), dim3(256), 0, stream,
                     bitmat, kxg, kvg);
  hipLaunchKernelGGL(scan_kernel, dim3(B_ * H_), dim3(256), 0, stream,
                     kxg, kvg, yg);
  hipLaunchKernelGGL(out_kernel, dim3(B_ * T_), dim3(256), 0, stream,
                     yg, e0, e1, out);
}